// Round 15
// baseline (733.746 us; speedup 1.0000x reference)
//
#include <hip/hip_runtime.h>

typedef unsigned short u16;
typedef unsigned int u32;
typedef __attribute__((ext_vector_type(8))) short bf16x8;
typedef __attribute__((ext_vector_type(4))) float f32x4;
typedef __attribute__((ext_vector_type(4))) int i32x4;

#define DEV __device__ __forceinline__

DEV u16 f2bf(float f){
  unsigned u = __float_as_uint(f);
  u += 0x7fffu + ((u >> 16) & 1u);
  return (u16)(u >> 16);
}
DEV float bf2f(u16 h){ return __uint_as_float(((unsigned)h) << 16); }

// Inverse spiral map: pixel index (0..80) -> spiral token position (0..80).
DEV int spiral_t(int pix){
  int px = pix / 9, py = pix % 9;
  int dr = px - 4, dc = py - 4;
  int ar = dr < 0 ? -dr : dr, ac = dc < 0 ? -dc : dc;
  int r = ar > ac ? ar : ac;
  if (r == 0) return 0;
  int start = 1 + 4*r*(r-1);
  if (dr == -r && dc >= -r+1) return start + dc + r - 1;
  if (dc == r)  return start + 2*r + dr + r - 1;
  if (dr == r)  return start + 4*r + dc + r;
  return start + 6*r + dr + r;
}

// ---------------- weight prep: Wt2 (conv2d tiles, BN folded)
__global__ __launch_bounds__(256) void k_wt(const float* __restrict__ w2c,
                                            const float* __restrict__ g2,
                                            const float* __restrict__ v2,
                                            u16* __restrict__ Wt2){
  int idx = blockIdx.x*256 + threadIdx.x;
  if (idx >= 72*64*32) return;
  int kk = idx & 31;
  int o  = (idx >> 5) & 63;
  int tile = idx >> 11;          // 0..71
  int dxy = tile >> 3;           // 0..8
  int chunk = tile & 7;          // 0..7
  int ch = chunk*32 + kk;        // padded channel
  float v = 0.f;
  if (ch < 240){
    float s2 = g2[o] * rsqrtf(v2[o] + 1e-5f);
    v = w2c[(o*240 + ch)*9 + dxy] * s2;
  }
  Wt2[idx] = f2bf(v);
}

// ---------------- FUSED conv3d + conv2d MFMA GEMM + BN + ReLU + pos_emb + LN1/tsum/SToken
// k_cv23: conv3d computed IN-BLOCK directly into the image LDS (no h1 HBM round-trip).
// Each thread owns a (img,pix,co) column: 27 w3 weights in VGPRs, 3-slice register
// window slides down dd reading x from global (L1-resident, guarded loads preserve
// v3's exact FMA order -> bit-identical h). Then the proven v9 GEMM: depth-2 B
// pipeline (3-buffer rotation), setprio, fused LN epilogue, split-k squeeze.
__global__ __launch_bounds__(256, 2) void k_cv23(const float* __restrict__ x,
    const float* __restrict__ w3, const float* __restrict__ b3,
    const float* __restrict__ g3, const float* __restrict__ be3,
    const float* __restrict__ m3, const float* __restrict__ v3,
    const u16* __restrict__ Wt2,
    const float* __restrict__ b2c, const float* __restrict__ g2,
    const float* __restrict__ be2, const float* __restrict__ m2,
    const float* __restrict__ v2,
    const float* __restrict__ pos_emb, const float* __restrict__ cls_tok,
    const float* __restrict__ ln1_g, const float* __restrict__ ln1_b,
    const float* __restrict__ Wst, const float* __restrict__ bst,
    const float* __restrict__ bias_st,
    u16* __restrict__ xn, float* __restrict__ tsum, float* __restrict__ sqs){
  // rows r in [0,162) at r*496 (480B data + 16B zero-ch-pad); zrow (496B zeros) at 80352
  __shared__ __align__(16) char smem[80848];
  const int ZROW = 80352;
  int tid = threadIdx.x;
  int wv = tid >> 6, ln = tid & 63;
  int lq = ln >> 4, lr = ln & 15;
  int img0 = blockIdx.x*2;

  int bln = lr*32 + lq*8;    // u16 offset of this lane's B-frag within a [64o][32k] tile

#define LOADB(TAP, C, B)                                                        \
    { const u16* Bt_ = Wt2 + (TAP)*16384 + bln;                                 \
      _Pragma("unroll")                                                         \
      for (int kk=0;kk<2;kk++)                                                  \
        _Pragma("unroll")                                                       \
        for (int j=0;j<4;j++)                                                   \
          B[kk][j] = *(const bf16x8*)(Bt_ + ((C)*2+kk)*2048 + j*512); }

  // B prologue (tap0 chunks 0,1,2): latency hides under the conv3d phase.
  bf16x8 bB0[2][4], bB1[2][4], bB2[2][4];
  LOADB(0, 0, bB0);
  LOADB(0, 1, bB1);
  LOADB(0, 2, bB2);

  // zero fills: per-row ch-pad [480,496) + zrow
  for (int r = tid; r < 162; r += 256)
    *(i32x4*)(smem + r*496 + 480) = (i32x4){0,0,0,0};
  if (tid < 31) *(i32x4*)(smem + ZROW + tid*16) = (i32x4){0,0,0,0};

  // ---- conv3d: compute 2 images directly into image-LDS rows ----
  for (int c = tid; c < 1296; c += 256){
    int img = c / 648, rem = c % 648;
    int pix = rem >> 3, co = rem & 7;
    int px = pix / 9, py = pix % 9;
    const float* xin = x + (size_t)(img0+img)*2430 + px*9 + py;
    int offs[9]; bool okf[9];
    #pragma unroll
    for (int kx=0;kx<3;kx++)
      #pragma unroll
      for (int ky=0;ky<3;ky++){
        int q = kx*3+ky;
        okf[q]  = ((unsigned)(px+kx-1) < 9u) && ((unsigned)(py+ky-1) < 9u);
        offs[q] = (kx-1)*9 + (ky-1);
      }
    float wp[27];
    #pragma unroll
    for (int q=0;q<27;q++) wp[q] = w3[co*27+q];
    float scv = g3[co]*rsqrtf(v3[co]+1e-5f);
    float shv = (b3[co]-m3[co])*scv + be3[co];

    float s0[9], s1[9], s2[9];
#define LSLG(S, DD2)                                                          \
    { int dd2_ = (DD2);                                                       \
      if ((unsigned)dd2_ < 30u){                                              \
        const float* xr_ = xin + dd2_*81;                                     \
        _Pragma("unroll")                                                     \
        for (int q=0;q<9;q++) S[q] = okf[q] ? xr_[offs[q]] : 0.f;             \
      } else {                                                                \
        _Pragma("unroll")                                                     \
        for (int q=0;q<9;q++) S[q] = 0.f;                                     \
      } }
#define DOT3(A, SA, SB, SC)                                                   \
    { A = 0.f;                                                                \
      _Pragma("unroll")                                                       \
      for (int q=0;q<9;q++) A = fmaf(SA[q], wp[q], A);                        \
      _Pragma("unroll")                                                       \
      for (int q=0;q<9;q++) A = fmaf(SB[q], wp[9+q], A);                      \
      _Pragma("unroll")                                                       \
      for (int q=0;q<9;q++) A = fmaf(SC[q], wp[18+q], A); }

    LSLG(s0, -1); LSLG(s1, 0); LSLG(s2, 1);
    u16 outv[30];
    #pragma unroll
    for (int d3 = 0; d3 < 30; d3 += 3){
      float a;
      DOT3(a, s0, s1, s2);
      outv[d3] = f2bf(fmaxf(fmaf(a, scv, shv), 0.f));
      LSLG(s0, d3+2);
      DOT3(a, s1, s2, s0);
      outv[d3+1] = f2bf(fmaxf(fmaf(a, scv, shv), 0.f));
      LSLG(s1, d3+3);
      DOT3(a, s2, s0, s1);
      outv[d3+2] = f2bf(fmaxf(fmaf(a, scv, shv), 0.f));
      LSLG(s2, d3+4);
    }
#undef LSLG
#undef DOT3
    u32* orow = (u32*)(smem + (img*81+pix)*496 + co*60);
    #pragma unroll
    for (int q=0;q<15;q++) orow[q] = ((u32)outv[2*q+1] << 16) | (u32)outv[2*q];
  }
  __syncthreads();

  // ---- GEMM (v9, unchanged) ----
  f32x4 acc[3][4];
  #pragma unroll
  for (int i=0;i<3;i++)
    #pragma unroll
    for (int j=0;j<4;j++) acc[i][j] = (f32x4){0.f,0.f,0.f,0.f};

#define CALCADDR(TAP, A0, A1, A13)                                              \
  { int dx = (TAP)/3 - 1, dy = (TAP)%3 - 1;                                     \
    _Pragma("unroll")                                                           \
    for (int rt=0;rt<3;rt++){                                                   \
      int row = (wv*3+rt)*16 + lr;                                              \
      int pix = row % 81;                                                       \
      int px = pix/9, py = pix%9;                                               \
      int px2 = px + dx, py2 = py + dy;                                         \
      bool valid = (row < 162) && ((unsigned)px2 < 9u) && ((unsigned)py2 < 9u); \
      int nrow = (row - pix) + px2*9 + py2;                                     \
      int base = valid ? nrow*496 : ZROW;                                       \
      A0[rt]  = base + lq*16;                                                   \
      A1[rt]  = base + 64 + lq*16;                                              \
      A13[rt] = (lq == 3) ? ZROW : (A1[rt] + 384);                              \
    } }

#define LOADA(C, SA0, SA1, SA13, A0, A1)                                        \
    { _Pragma("unroll")                                                         \
      for (int rt=0;rt<3;rt++){                                                 \
        A0[rt] = *(const bf16x8*)(smem + SA0[rt] + (C)*128);                    \
        A1[rt] = *(const bf16x8*)(smem + ((C)==3 ? SA13[rt]                     \
                                                 : SA1[rt] + (C)*128)); } }

#define DOMFMA(B, A0, A1)                                                       \
    { __builtin_amdgcn_s_setprio(1);                                            \
      _Pragma("unroll")                                                         \
      for (int rt=0;rt<3;rt++)                                                  \
        _Pragma("unroll")                                                       \
        for (int j=0;j<4;j++)                                                   \
          acc[rt][j] = __builtin_amdgcn_mfma_f32_16x16x32_bf16(A0[rt], B[0][j], acc[rt][j], 0, 0, 0); \
      _Pragma("unroll")                                                         \
      for (int rt=0;rt<3;rt++)                                                  \
        _Pragma("unroll")                                                       \
        for (int j=0;j<4;j++)                                                   \
          acc[rt][j] = __builtin_amdgcn_mfma_f32_16x16x32_bf16(A1[rt], B[1][j], acc[rt][j], 0, 0, 0); \
      __builtin_amdgcn_s_setprio(0); }

#define TAPBODY(TAPV, BA, BB, BC)                                               \
  { int ntap_ = (TAPV) < 8 ? (TAPV)+1 : 8;                                      \
    DOMFMA(BA, aAX0, aAX1);                                                     \
    LOADB((TAPV), 3, BA); LOADA(2, aC0, aC1, aC13, aAX0, aAX1);                 \
    DOMFMA(BB, aAY0, aAY1);                                                     \
    LOADB(ntap_, 0, BB); CALCADDR(ntap_, aN0, aN1, aN13);                       \
    LOADA(3, aC0, aC1, aC13, aAY0, aAY1);                                       \
    DOMFMA(BC, aAX0, aAX1);                                                     \
    LOADB(ntap_, 1, BC); LOADA(0, aN0, aN1, aN13, aAX0, aAX1);                  \
    DOMFMA(BA, aAY0, aAY1);                                                     \
    LOADB(ntap_, 2, BA); LOADA(1, aN0, aN1, aN13, aAY0, aAY1);                  \
    _Pragma("unroll")                                                           \
    for (int rt=0;rt<3;rt++){ aC0[rt]=aN0[rt]; aC1[rt]=aN1[rt]; aC13[rt]=aN13[rt]; } }

  int aC0[3], aC1[3], aC13[3];
  int aN0[3], aN1[3], aN13[3];
  bf16x8 aAX0[3], aAX1[3], aAY0[3], aAY1[3];

  CALCADDR(0, aC0, aC1, aC13);
  LOADA(0, aC0, aC1, aC13, aAX0, aAX1);
  LOADA(1, aC0, aC1, aC13, aAY0, aAY1);

  for (int t3 = 0; t3 < 9; t3 += 3){
    TAPBODY(t3+0, bB0, bB1, bB2);
    TAPBODY(t3+1, bB1, bB2, bB0);
    TAPBODY(t3+2, bB2, bB0, bB1);
  }
#undef CALCADDR
#undef LOADB
#undef LOADA
#undef DOMFMA
#undef TAPBODY

  __syncthreads();   // all image-LDS reads done; smem reusable for reductions

  float t2c[4], lg[4], lb[4];
  #pragma unroll
  for (int j=0;j<4;j++){
    int col = j*16 + lr;
    float s2 = g2[col]*rsqrtf(v2[col]+1e-5f);
    t2c[j] = (b2c[col]-m2[col])*s2 + be2[col];
    lg[j] = ln1_g[col]; lb[j] = ln1_b[col];
  }

  float st0[4]={0,0,0,0}, st1[4]={0,0,0,0};
  float sx0[4]={0,0,0,0}, sx1[4]={0,0,0,0};

  #pragma unroll
  for (int rt=0;rt<3;rt++){
    #pragma unroll
    for (int e=0;e<4;e++){
      int row = (wv*3+rt)*16 + lq*4 + e;
      if (row < 162){
        int im = (row >= 81);
        int pix = row - im*81;
        int tsp = spiral_t(pix);
        const float* pe = pos_emb + (1+tsp)*64;
        float y[4], m1 = 0.f, m2v = 0.f;
        #pragma unroll
        for (int j=0;j<4;j++){
          y[j] = fmaxf(acc[rt][j][e] + t2c[j], 0.f) + pe[j*16+lr];
          m1 += y[j]; m2v = fmaf(y[j], y[j], m2v);
        }
        #pragma unroll
        for (int off=1; off<16; off<<=1){
          m1  += __shfl_xor(m1,  off, 64);
          m2v += __shfl_xor(m2v, off, 64);
        }
        float mean = m1*(1.f/64.f);
        float var  = m2v*(1.f/64.f) - mean*mean;
        float rs = rsqrtf(var + 1e-5f);
        u16* dst = xn + ((size_t)(img0+im)*82 + 1 + tsp)*64;
        #pragma unroll
        for (int j=0;j<4;j++){
          float xnv = (y[j]-mean)*rs*lg[j] + lb[j];
          dst[j*16+lr] = f2bf(xnv);
          if (im == 0){ st0[j] += y[j]; sx0[j] += xnv; }
          else        { st1[j] += y[j]; sx1[j] += xnv; }
        }
      }
    }
  }

  #pragma unroll
  for (int j=0;j<4;j++){
    st0[j] += __shfl_xor(st0[j],16,64); st0[j] += __shfl_xor(st0[j],32,64);
    st1[j] += __shfl_xor(st1[j],16,64); st1[j] += __shfl_xor(st1[j],32,64);
    sx0[j] += __shfl_xor(sx0[j],16,64); sx0[j] += __shfl_xor(sx0[j],32,64);
    sx1[j] += __shfl_xor(sx1[j],16,64); sx1[j] += __shfl_xor(sx1[j],32,64);
  }
  float* partT = (float*)smem;            // [4 wv][2 img][64 d]
  float* partX = (float*)(smem + 2048);
  float* xsumL = (float*)(smem + 4096);
  if (lq == 0){
    #pragma unroll
    for (int j=0;j<4;j++){
      partT[wv*128 +       j*16+lr] = st0[j];
      partT[wv*128 + 64  + j*16+lr] = st1[j];
      partX[wv*128 +       j*16+lr] = sx0[j];
      partX[wv*128 + 64  + j*16+lr] = sx1[j];
    }
  }
  __syncthreads();
  if (tid < 128){
    int im = tid >> 6, d = tid & 63;
    float tt = partT[im*64+d] + partT[128+im*64+d] + partT[256+im*64+d] + partT[384+im*64+d];
    float xx = partX[im*64+d] + partX[128+im*64+d] + partX[256+im*64+d] + partX[384+im*64+d];
    float clsv = cls_tok[d] + pos_emb[d];
    float c1v = clsv, c2v = clsv*clsv;
    #pragma unroll
    for (int off=1; off<64; off<<=1){ c1v += __shfl_xor(c1v, off, 64); c2v += __shfl_xor(c2v, off, 64); }
    float cm = c1v*(1.f/64.f), cv = c2v*(1.f/64.f) - cm*cm;
    float cxn = (clsv - cm)*rsqrtf(cv + 1e-5f)*ln1_g[d] + ln1_b[d];
    xn[((size_t)(img0+im)*82)*64 + d] = f2bf(cxn);
    tsum[(size_t)(img0+im)*64 + d] = tt + clsv;
    xsumL[im*64 + d] = (xx + cxn) * (1.f/82.f);
  }
  __syncthreads();
  {
    int im = tid >> 7, d2 = tid & 127;
    int d = d2 >> 1, half = d2 & 1;
    float a = 0.f;
    int k0 = half*32;
    #pragma unroll
    for (int k=0;k<32;k++) a = fmaf(xsumL[im*64 + k0+k], Wst[(k0+k)*64+d], a);
    a += __shfl_xor(a, 1, 64);
    if (half == 0){
      a += bst[d];
      a = fmaxf(a, 0.f);
      a = 1.f/(1.f + __expf(-a));
      sqs[(size_t)(img0+im)*64 + d] = a + bias_st[d];
    }
  }
}

// ---------------- FUSED B/C/delta GEMM + S6 prep + scan + pool + LN2 + MLP (block = batch)
__global__ __launch_bounds__(256, 2) void k_fuse(const u16* __restrict__ xn,
    const float* __restrict__ tsum, const float* __restrict__ sqs,
    const float* __restrict__ Wb, const float* __restrict__ Wc, const float* __restrict__ Wd,
    const float* __restrict__ bbv, const float* __restrict__ bcv, const float* __restrict__ bdv,
    const float* __restrict__ delta_p, const float* __restrict__ A_p,
    const float* __restrict__ ln2_g, const float* __restrict__ ln2_b,
    const float* __restrict__ Wm1, const float* __restrict__ bm1,
    const float* __restrict__ Wm2, const float* __restrict__ bm2,
    float* __restrict__ out){
  __shared__ __align__(16) char xnL[96*128];   // swizzled rows: byte ^ ((row&7)<<4)
  __shared__ u16 AxL[96][66], BxL[96][66], CxL[96][66];
  int tid = threadIdx.x;
  int wv = tid >> 6, ln = tid & 63;
  int lq = ln >> 4, lr = ln & 15;
  int b = blockIdx.x;

  // B-frags first (L2-hot): cc = wv*16+lr for each of Wb/Wc/Wd
  bf16x8 bfr[3][2];
  {
    int cc = wv*16 + lr;
    const float* Ws[3] = {Wb, Wc, Wd};
    #pragma unroll
    for (int w=0;w<3;w++)
      #pragma unroll
      for (int kk=0;kk<2;kk++){
        int k0 = kk*32 + lq*8;
        bf16x8 f;
        #pragma unroll
        for (int e=0;e<8;e++) f[e] = (short)f2bf(Ws[w][(k0+e)*64 + cc]);
        bfr[w][kk] = f;
      }
  }

  // stage xn[b] rows 0..81 (swizzled), zero rows 82..95
  {
    const u16* src = xn + (size_t)b*82*64;
    for (int idx = tid; idx < 656; idx += 256){       // 82 rows x 8 x 16B
      int r = idx >> 3, c = idx & 7;
      *(i32x4*)(xnL + r*128 + ((c*16) ^ ((r&7)<<4))) = *(const i32x4*)(src + idx*8);
    }
    for (int idx = tid; idx < 112; idx += 256){       // rows 82..95
      int r = 82 + (idx >> 3), c = idx & 7;
      *(i32x4*)(xnL + r*128 + ((c*16) ^ ((r&7)<<4))) = (i32x4){0,0,0,0};
    }
  }
  __syncthreads();

  f32x4 acc[6][3];
  #pragma unroll
  for (int i=0;i<6;i++)
    #pragma unroll
    for (int w=0;w<3;w++) acc[i][w] = (f32x4){0.f,0.f,0.f,0.f};

  #pragma unroll
  for (int rt=0;rt<6;rt++){
    int row = rt*16 + lr;
    bf16x8 afr[2];
    #pragma unroll
    for (int kk=0;kk<2;kk++)
      afr[kk] = *(const bf16x8*)(xnL + row*128 + ((kk*64 + lq*16) ^ ((row&7)<<4)));
    #pragma unroll
    for (int kk=0;kk<2;kk++)
      #pragma unroll
      for (int w=0;w<3;w++)
        acc[rt][w] = __builtin_amdgcn_mfma_f32_16x16x32_bf16(afr[kk], bfr[w][kk], acc[rt][w], 0, 0, 0);
  }

  // epilogue: lane holds (B0, C, Draw) for d = wv*16+lr at token t
  {
    int d = wv*16 + lr;
    float bB = bbv[d], bC = bcv[d], bD = bdv[d];
    #pragma unroll
    for (int rt=0;rt<6;rt++){
      #pragma unroll
      for (int e=0;e<4;e++){
        int t = rt*16 + lq*4 + e;
        if (t < 82){
          float B0 = acc[rt][0][e] + bB;
          float Cv = acc[rt][1][e] + bC;
          float Dr = acc[rt][2][e] + bD + delta_p[t*64+d];
          float D  = 1.f/(1.f + __expf(-Dr));
          float xv = bf2f(*(const u16*)(xnL + t*128 + ((d*2) ^ ((t&7)<<4))));
          AxL[t][d] = f2bf(D * A_p[t*64+d]);
          BxL[t][d] = f2bf(D * B0 * xv);
          CxL[t][d] = f2bf(Cv);
        }
      }
    }
  }
  __syncthreads();

  if (wv == 0){
    int d = ln;
    float sq = sqs[(size_t)b*64 + d];
    float s = 0.f, racc = 0.f;
    for (int t = 0; t < 82; t++){
      float a  = bf2f(AxL[t][d]);
      float bx = bf2f(BxL[t][d]);
      float c  = bf2f(CxL[t][d]);
      float xv = bf2f(*(const u16*)(xnL + t*128 + ((d*2) ^ ((t&7)<<4))));
      s = fmaf(a, s, bx);
      float o = fmaf(c, s, sq*xv);
      float z = 1.f/(1.f + __expf(-xv));
      racc = fmaf(o, z, racc);
    }
    float pooled = (tsum[(size_t)b*64 + d] + racc) * (1.f/82.f);
    float s1 = pooled, s2v = pooled*pooled;
    #pragma unroll
    for (int off=32; off>0; off>>=1){ s1 += __shfl_xor(s1, off, 64); s2v += __shfl_xor(s2v, off, 64); }
    float mean = s1*(1.f/64.f), var = s2v*(1.f/64.f) - mean*mean;
    float yn = (pooled - mean)*rsqrtf(var + 1e-5f)*ln2_g[d] + ln2_b[d];
    float a1 = bm1[d];
    for (int k=0;k<64;k++) a1 = fmaf(__shfl(yn, k, 64), Wm1[k*64+d], a1);
    float hg = 0.5f*a1*(1.f + erff(a1*0.70710678118654752f));
    float a2 = bm2[d];
    for (int k=0;k<64;k++) a2 = fmaf(__shfl(hg, k, 64), Wm2[k*64+d], a2);
    out[(size_t)b*64 + d] = pooled + a2;
  }
}

extern "C" void kernel_launch(void* const* d_in, const int* in_sizes, int n_in,
                              void* d_out, int out_size, void* d_ws, size_t ws_size,
                              hipStream_t stream){
  const float* x       = (const float*)d_in[0];
  const float* w3      = (const float*)d_in[1];
  const float* b3      = (const float*)d_in[2];
  const float* g3      = (const float*)d_in[3];
  const float* be3     = (const float*)d_in[4];
  const float* m3      = (const float*)d_in[5];
  const float* v3      = (const float*)d_in[6];
  const float* w2c     = (const float*)d_in[7];
  const float* b2c     = (const float*)d_in[8];
  const float* g2      = (const float*)d_in[9];
  const float* be2     = (const float*)d_in[10];
  const float* m2      = (const float*)d_in[11];
  const float* v2      = (const float*)d_in[12];
  const float* pos_emb = (const float*)d_in[13];
  const float* cls_tok = (const float*)d_in[14];
  const float* ln1_g   = (const float*)d_in[15];
  const float* ln1_b   = (const float*)d_in[16];
  const float* Wb      = (const float*)d_in[17];
  const float* bbv     = (const float*)d_in[18];
  const float* Wc      = (const float*)d_in[19];
  const float* bc      = (const float*)d_in[20];
  const float* Wd      = (const float*)d_in[21];
  const float* bd      = (const float*)d_in[22];
  const float* delta_p = (const float*)d_in[23];
  const float* A_p     = (const float*)d_in[24];
  const float* Wst     = (const float*)d_in[25];
  const float* bst     = (const float*)d_in[26];
  const float* bias_st = (const float*)d_in[27];
  const float* ln2_g   = (const float*)d_in[28];
  const float* ln2_b   = (const float*)d_in[29];
  const float* Wm1     = (const float*)d_in[30];
  const float* bm1     = (const float*)d_in[31];
  const float* Wm2     = (const float*)d_in[32];
  const float* bm2     = (const float*)d_in[33];

  // workspace layout (bytes), peak = 204,660,736:
  //   Wt2  [159252480,  159547392)  (wt -> k_cv23)
  //   xn   [159571968,  202563584)  bf16 [4096][82][64]  (k_cv23 -> k_fuse)
  //   tsum [202563584,  203612160)  f32  [4096][64]      (k_cv23 -> k_fuse)
  //   sqs  [203612160,  204660736)  f32  [4096][64]      (k_cv23 -> k_fuse)
  //   (h1 region [0,159252480) no longer used -- conv3d fused into k_cv23)
  char* ws = (char*)d_ws;
  u16*   Wt2  = (u16*)(ws + 159252480);
  u16*   xnb  = (u16*)(ws + 159571968);
  float* tsum = (float*)(ws + 202563584);
  float* sqs  = (float*)(ws + 203612160);

  k_wt   <<<576,  256, 0, stream>>>(w2c, g2, v2, Wt2);
  k_cv23 <<<2048, 256, 0, stream>>>(x, w3, b3, g3, be3, m3, v3, Wt2,
                                    b2c, g2, be2, m2, v2,
                                    pos_emb, cls_tok, ln1_g, ln1_b,
                                    Wst, bst, bias_st, xnb, tsum, sqs);
  k_fuse <<<4096, 256, 0, stream>>>(xnb, tsum, sqs, Wb, Wc, Wd, bbv, bc, bd,
                                    delta_p, A_p, ln2_g, ln2_b,
                                    Wm1, bm1, Wm2, bm2, (float*)d_out);
}

// Round 16
// 684.621 us; speedup vs baseline: 1.0718x; 1.0718x over previous
//
#include <hip/hip_runtime.h>

typedef unsigned short u16;
typedef unsigned int u32;
typedef __attribute__((ext_vector_type(8))) short bf16x8;
typedef __attribute__((ext_vector_type(4))) float f32x4;
typedef __attribute__((ext_vector_type(4))) int i32x4;

#define DEV __device__ __forceinline__

DEV u16 f2bf(float f){
  unsigned u = __float_as_uint(f);
  u += 0x7fffu + ((u >> 16) & 1u);
  return (u16)(u >> 16);
}
DEV float bf2f(u16 h){ return __uint_as_float(((unsigned)h) << 16); }

// Inverse spiral map: pixel index (0..80) -> spiral token position (0..80).
DEV int spiral_t(int pix){
  int px = pix / 9, py = pix % 9;
  int dr = px - 4, dc = py - 4;
  int ar = dr < 0 ? -dr : dr, ac = dc < 0 ? -dc : dc;
  int r = ar > ac ? ar : ac;
  if (r == 0) return 0;
  int start = 1 + 4*r*(r-1);
  if (dr == -r && dc >= -r+1) return start + dc + r - 1;
  if (dc == r)  return start + 2*r + dr + r - 1;
  if (dr == r)  return start + 4*r + dc + r;
  return start + 6*r + dr + r;
}

// ---------------- weight prep: Wt2 (conv2d tiles, BN folded)
__global__ __launch_bounds__(256) void k_wt(const float* __restrict__ w2c,
                                            const float* __restrict__ g2,
                                            const float* __restrict__ v2,
                                            u16* __restrict__ Wt2){
  int idx = blockIdx.x*256 + threadIdx.x;
  if (idx >= 72*64*32) return;
  int kk = idx & 31;
  int o  = (idx >> 5) & 63;
  int tile = idx >> 11;          // 0..71
  int dxy = tile >> 3;           // 0..8
  int chunk = tile & 7;          // 0..7
  int ch = chunk*32 + kk;        // padded channel
  float v = 0.f;
  if (ch < 240){
    float s2 = g2[o] * rsqrtf(v2[o] + 1e-5f);
    v = w2c[(o*240 + ch)*9 + dxy] * s2;
  }
  Wt2[idx] = f2bf(v);
}

// ---------------- FUSED conv3d + conv2d MFMA GEMM + BN + ReLU + pos_emb + LN1/tsum/SToken
// v2 of the fusion: B prologue moved AFTER the conv3d phase -- round 15 held
// bB0/bB1/bB2 (48 VGPRs) live across conv3d's ~95-reg working set -> scratch
// spill (WRITE 44->818MB). Phase-max pressure now max(conv3d~95, GEMM=128).
__global__ __launch_bounds__(256, 2) void k_cv23(const float* __restrict__ x,
    const float* __restrict__ w3, const float* __restrict__ b3,
    const float* __restrict__ g3, const float* __restrict__ be3,
    const float* __restrict__ m3, const float* __restrict__ v3,
    const u16* __restrict__ Wt2,
    const float* __restrict__ b2c, const float* __restrict__ g2,
    const float* __restrict__ be2, const float* __restrict__ m2,
    const float* __restrict__ v2,
    const float* __restrict__ pos_emb, const float* __restrict__ cls_tok,
    const float* __restrict__ ln1_g, const float* __restrict__ ln1_b,
    const float* __restrict__ Wst, const float* __restrict__ bst,
    const float* __restrict__ bias_st,
    u16* __restrict__ xn, float* __restrict__ tsum, float* __restrict__ sqs){
  // rows r in [0,162) at r*496 (480B data + 16B zero-ch-pad); zrow (496B zeros) at 80352
  __shared__ __align__(16) char smem[80848];
  const int ZROW = 80352;
  int tid = threadIdx.x;
  int wv = tid >> 6, ln = tid & 63;
  int lq = ln >> 4, lr = ln & 15;
  int img0 = blockIdx.x*2;

  int bln = lr*32 + lq*8;    // u16 offset of this lane's B-frag within a [64o][32k] tile

#define LOADB(TAP, C, B)                                                        \
    { const u16* Bt_ = Wt2 + (TAP)*16384 + bln;                                 \
      _Pragma("unroll")                                                         \
      for (int kk=0;kk<2;kk++)                                                  \
        _Pragma("unroll")                                                       \
        for (int j=0;j<4;j++)                                                   \
          B[kk][j] = *(const bf16x8*)(Bt_ + ((C)*2+kk)*2048 + j*512); }

  // zero fills: per-row ch-pad [480,496) + zrow
  for (int r = tid; r < 162; r += 256)
    *(i32x4*)(smem + r*496 + 480) = (i32x4){0,0,0,0};
  if (tid < 31) *(i32x4*)(smem + ZROW + tid*16) = (i32x4){0,0,0,0};

  // ---- conv3d: compute 2 images directly into image-LDS rows ----
  for (int c = tid; c < 1296; c += 256){
    int img = c / 648, rem = c % 648;
    int pix = rem >> 3, co = rem & 7;
    int px = pix / 9, py = pix % 9;
    const float* xin = x + (size_t)(img0+img)*2430 + px*9 + py;
    int offs[9]; bool okf[9];
    #pragma unroll
    for (int kx=0;kx<3;kx++)
      #pragma unroll
      for (int ky=0;ky<3;ky++){
        int q = kx*3+ky;
        okf[q]  = ((unsigned)(px+kx-1) < 9u) && ((unsigned)(py+ky-1) < 9u);
        offs[q] = (kx-1)*9 + (ky-1);
      }
    float wp[27];
    #pragma unroll
    for (int q=0;q<27;q++) wp[q] = w3[co*27+q];
    float scv = g3[co]*rsqrtf(v3[co]+1e-5f);
    float shv = (b3[co]-m3[co])*scv + be3[co];

    float s0[9], s1[9], s2[9];
#define LSLG(S, DD2)                                                          \
    { int dd2_ = (DD2);                                                       \
      if ((unsigned)dd2_ < 30u){                                              \
        const float* xr_ = xin + dd2_*81;                                     \
        _Pragma("unroll")                                                     \
        for (int q=0;q<9;q++) S[q] = okf[q] ? xr_[offs[q]] : 0.f;             \
      } else {                                                                \
        _Pragma("unroll")                                                     \
        for (int q=0;q<9;q++) S[q] = 0.f;                                     \
      } }
#define DOT3(A, SA, SB, SC)                                                   \
    { A = 0.f;                                                                \
      _Pragma("unroll")                                                       \
      for (int q=0;q<9;q++) A = fmaf(SA[q], wp[q], A);                        \
      _Pragma("unroll")                                                       \
      for (int q=0;q<9;q++) A = fmaf(SB[q], wp[9+q], A);                      \
      _Pragma("unroll")                                                       \
      for (int q=0;q<9;q++) A = fmaf(SC[q], wp[18+q], A); }

    LSLG(s0, -1); LSLG(s1, 0); LSLG(s2, 1);
    u16 outv[30];
    #pragma unroll
    for (int d3 = 0; d3 < 30; d3 += 3){
      float a;
      DOT3(a, s0, s1, s2);
      outv[d3] = f2bf(fmaxf(fmaf(a, scv, shv), 0.f));
      LSLG(s0, d3+2);
      DOT3(a, s1, s2, s0);
      outv[d3+1] = f2bf(fmaxf(fmaf(a, scv, shv), 0.f));
      LSLG(s1, d3+3);
      DOT3(a, s2, s0, s1);
      outv[d3+2] = f2bf(fmaxf(fmaf(a, scv, shv), 0.f));
      LSLG(s2, d3+4);
    }
#undef LSLG
#undef DOT3
    u32* orow = (u32*)(smem + (img*81+pix)*496 + co*60);
    #pragma unroll
    for (int q=0;q<15;q++) orow[q] = ((u32)outv[2*q+1] << 16) | (u32)outv[2*q];
  }

  // B prologue (tap0 chunks 0,1,2) AFTER conv3d: conv3d regs are dead here,
  // loads overlap the barrier drain below.
  bf16x8 bB0[2][4], bB1[2][4], bB2[2][4];
  LOADB(0, 0, bB0);
  LOADB(0, 1, bB1);
  LOADB(0, 2, bB2);
  __syncthreads();

  // ---- GEMM (v9, unchanged) ----
  f32x4 acc[3][4];
  #pragma unroll
  for (int i=0;i<3;i++)
    #pragma unroll
    for (int j=0;j<4;j++) acc[i][j] = (f32x4){0.f,0.f,0.f,0.f};

#define CALCADDR(TAP, A0, A1, A13)                                              \
  { int dx = (TAP)/3 - 1, dy = (TAP)%3 - 1;                                     \
    _Pragma("unroll")                                                           \
    for (int rt=0;rt<3;rt++){                                                   \
      int row = (wv*3+rt)*16 + lr;                                              \
      int pix = row % 81;                                                       \
      int px = pix/9, py = pix%9;                                               \
      int px2 = px + dx, py2 = py + dy;                                         \
      bool valid = (row < 162) && ((unsigned)px2 < 9u) && ((unsigned)py2 < 9u); \
      int nrow = (row - pix) + px2*9 + py2;                                     \
      int base = valid ? nrow*496 : ZROW;                                       \
      A0[rt]  = base + lq*16;                                                   \
      A1[rt]  = base + 64 + lq*16;                                              \
      A13[rt] = (lq == 3) ? ZROW : (A1[rt] + 384);                              \
    } }

#define LOADA(C, SA0, SA1, SA13, A0, A1)                                        \
    { _Pragma("unroll")                                                         \
      for (int rt=0;rt<3;rt++){                                                 \
        A0[rt] = *(const bf16x8*)(smem + SA0[rt] + (C)*128);                    \
        A1[rt] = *(const bf16x8*)(smem + ((C)==3 ? SA13[rt]                     \
                                                 : SA1[rt] + (C)*128)); } }

#define DOMFMA(B, A0, A1)                                                       \
    { __builtin_amdgcn_s_setprio(1);                                            \
      _Pragma("unroll")                                                         \
      for (int rt=0;rt<3;rt++)                                                  \
        _Pragma("unroll")                                                       \
        for (int j=0;j<4;j++)                                                   \
          acc[rt][j] = __builtin_amdgcn_mfma_f32_16x16x32_bf16(A0[rt], B[0][j], acc[rt][j], 0, 0, 0); \
      _Pragma("unroll")                                                         \
      for (int rt=0;rt<3;rt++)                                                  \
        _Pragma("unroll")                                                       \
        for (int j=0;j<4;j++)                                                   \
          acc[rt][j] = __builtin_amdgcn_mfma_f32_16x16x32_bf16(A1[rt], B[1][j], acc[rt][j], 0, 0, 0); \
      __builtin_amdgcn_s_setprio(0); }

#define TAPBODY(TAPV, BA, BB, BC)                                               \
  { int ntap_ = (TAPV) < 8 ? (TAPV)+1 : 8;                                      \
    DOMFMA(BA, aAX0, aAX1);                                                     \
    LOADB((TAPV), 3, BA); LOADA(2, aC0, aC1, aC13, aAX0, aAX1);                 \
    DOMFMA(BB, aAY0, aAY1);                                                     \
    LOADB(ntap_, 0, BB); CALCADDR(ntap_, aN0, aN1, aN13);                       \
    LOADA(3, aC0, aC1, aC13, aAY0, aAY1);                                       \
    DOMFMA(BC, aAX0, aAX1);                                                     \
    LOADB(ntap_, 1, BC); LOADA(0, aN0, aN1, aN13, aAX0, aAX1);                  \
    DOMFMA(BA, aAY0, aAY1);                                                     \
    LOADB(ntap_, 2, BA); LOADA(1, aN0, aN1, aN13, aAY0, aAY1);                  \
    _Pragma("unroll")                                                           \
    for (int rt=0;rt<3;rt++){ aC0[rt]=aN0[rt]; aC1[rt]=aN1[rt]; aC13[rt]=aN13[rt]; } }

  int aC0[3], aC1[3], aC13[3];
  int aN0[3], aN1[3], aN13[3];
  bf16x8 aAX0[3], aAX1[3], aAY0[3], aAY1[3];

  CALCADDR(0, aC0, aC1, aC13);
  LOADA(0, aC0, aC1, aC13, aAX0, aAX1);
  LOADA(1, aC0, aC1, aC13, aAY0, aAY1);

  for (int t3 = 0; t3 < 9; t3 += 3){
    TAPBODY(t3+0, bB0, bB1, bB2);
    TAPBODY(t3+1, bB1, bB2, bB0);
    TAPBODY(t3+2, bB2, bB0, bB1);
  }
#undef CALCADDR
#undef LOADB
#undef LOADA
#undef DOMFMA
#undef TAPBODY

  __syncthreads();   // all image-LDS reads done; smem reusable for reductions

  float t2c[4], lg[4], lb[4];
  #pragma unroll
  for (int j=0;j<4;j++){
    int col = j*16 + lr;
    float s2 = g2[col]*rsqrtf(v2[col]+1e-5f);
    t2c[j] = (b2c[col]-m2[col])*s2 + be2[col];
    lg[j] = ln1_g[col]; lb[j] = ln1_b[col];
  }

  float st0[4]={0,0,0,0}, st1[4]={0,0,0,0};
  float sx0[4]={0,0,0,0}, sx1[4]={0,0,0,0};

  #pragma unroll
  for (int rt=0;rt<3;rt++){
    #pragma unroll
    for (int e=0;e<4;e++){
      int row = (wv*3+rt)*16 + lq*4 + e;
      if (row < 162){
        int im = (row >= 81);
        int pix = row - im*81;
        int tsp = spiral_t(pix);
        const float* pe = pos_emb + (1+tsp)*64;
        float y[4], m1 = 0.f, m2v = 0.f;
        #pragma unroll
        for (int j=0;j<4;j++){
          y[j] = fmaxf(acc[rt][j][e] + t2c[j], 0.f) + pe[j*16+lr];
          m1 += y[j]; m2v = fmaf(y[j], y[j], m2v);
        }
        #pragma unroll
        for (int off=1; off<16; off<<=1){
          m1  += __shfl_xor(m1,  off, 64);
          m2v += __shfl_xor(m2v, off, 64);
        }
        float mean = m1*(1.f/64.f);
        float var  = m2v*(1.f/64.f) - mean*mean;
        float rs = rsqrtf(var + 1e-5f);
        u16* dst = xn + ((size_t)(img0+im)*82 + 1 + tsp)*64;
        #pragma unroll
        for (int j=0;j<4;j++){
          float xnv = (y[j]-mean)*rs*lg[j] + lb[j];
          dst[j*16+lr] = f2bf(xnv);
          if (im == 0){ st0[j] += y[j]; sx0[j] += xnv; }
          else        { st1[j] += y[j]; sx1[j] += xnv; }
        }
      }
    }
  }

  #pragma unroll
  for (int j=0;j<4;j++){
    st0[j] += __shfl_xor(st0[j],16,64); st0[j] += __shfl_xor(st0[j],32,64);
    st1[j] += __shfl_xor(st1[j],16,64); st1[j] += __shfl_xor(st1[j],32,64);
    sx0[j] += __shfl_xor(sx0[j],16,64); sx0[j] += __shfl_xor(sx0[j],32,64);
    sx1[j] += __shfl_xor(sx1[j],16,64); sx1[j] += __shfl_xor(sx1[j],32,64);
  }
  float* partT = (float*)smem;            // [4 wv][2 img][64 d]
  float* partX = (float*)(smem + 2048);
  float* xsumL = (float*)(smem + 4096);
  if (lq == 0){
    #pragma unroll
    for (int j=0;j<4;j++){
      partT[wv*128 +       j*16+lr] = st0[j];
      partT[wv*128 + 64  + j*16+lr] = st1[j];
      partX[wv*128 +       j*16+lr] = sx0[j];
      partX[wv*128 + 64  + j*16+lr] = sx1[j];
    }
  }
  __syncthreads();
  if (tid < 128){
    int im = tid >> 6, d = tid & 63;
    float tt = partT[im*64+d] + partT[128+im*64+d] + partT[256+im*64+d] + partT[384+im*64+d];
    float xx = partX[im*64+d] + partX[128+im*64+d] + partX[256+im*64+d] + partX[384+im*64+d];
    float clsv = cls_tok[d] + pos_emb[d];
    float c1v = clsv, c2v = clsv*clsv;
    #pragma unroll
    for (int off=1; off<64; off<<=1){ c1v += __shfl_xor(c1v, off, 64); c2v += __shfl_xor(c2v, off, 64); }
    float cm = c1v*(1.f/64.f), cv = c2v*(1.f/64.f) - cm*cm;
    float cxn = (clsv - cm)*rsqrtf(cv + 1e-5f)*ln1_g[d] + ln1_b[d];
    xn[((size_t)(img0+im)*82)*64 + d] = f2bf(cxn);
    tsum[(size_t)(img0+im)*64 + d] = tt + clsv;
    xsumL[im*64 + d] = (xx + cxn) * (1.f/82.f);
  }
  __syncthreads();
  {
    int im = tid >> 7, d2 = tid & 127;
    int d = d2 >> 1, half = d2 & 1;
    float a = 0.f;
    int k0 = half*32;
    #pragma unroll
    for (int k=0;k<32;k++) a = fmaf(xsumL[im*64 + k0+k], Wst[(k0+k)*64+d], a);
    a += __shfl_xor(a, 1, 64);
    if (half == 0){
      a += bst[d];
      a = fmaxf(a, 0.f);
      a = 1.f/(1.f + __expf(-a));
      sqs[(size_t)(img0+im)*64 + d] = a + bias_st[d];
    }
  }
}

// ---------------- FUSED B/C/delta GEMM + S6 prep + scan + pool + LN2 + MLP (block = batch)
__global__ __launch_bounds__(256, 2) void k_fuse(const u16* __restrict__ xn,
    const float* __restrict__ tsum, const float* __restrict__ sqs,
    const float* __restrict__ Wb, const float* __restrict__ Wc, const float* __restrict__ Wd,
    const float* __restrict__ bbv, const float* __restrict__ bcv, const float* __restrict__ bdv,
    const float* __restrict__ delta_p, const float* __restrict__ A_p,
    const float* __restrict__ ln2_g, const float* __restrict__ ln2_b,
    const float* __restrict__ Wm1, const float* __restrict__ bm1,
    const float* __restrict__ Wm2, const float* __restrict__ bm2,
    float* __restrict__ out){
  __shared__ __align__(16) char xnL[96*128];   // swizzled rows: byte ^ ((row&7)<<4)
  __shared__ u16 AxL[96][66], BxL[96][66], CxL[96][66];
  int tid = threadIdx.x;
  int wv = tid >> 6, ln = tid & 63;
  int lq = ln >> 4, lr = ln & 15;
  int b = blockIdx.x;

  // B-frags first (L2-hot): cc = wv*16+lr for each of Wb/Wc/Wd
  bf16x8 bfr[3][2];
  {
    int cc = wv*16 + lr;
    const float* Ws[3] = {Wb, Wc, Wd};
    #pragma unroll
    for (int w=0;w<3;w++)
      #pragma unroll
      for (int kk=0;kk<2;kk++){
        int k0 = kk*32 + lq*8;
        bf16x8 f;
        #pragma unroll
        for (int e=0;e<8;e++) f[e] = (short)f2bf(Ws[w][(k0+e)*64 + cc]);
        bfr[w][kk] = f;
      }
  }

  // stage xn[b] rows 0..81 (swizzled), zero rows 82..95
  {
    const u16* src = xn + (size_t)b*82*64;
    for (int idx = tid; idx < 656; idx += 256){       // 82 rows x 8 x 16B
      int r = idx >> 3, c = idx & 7;
      *(i32x4*)(xnL + r*128 + ((c*16) ^ ((r&7)<<4))) = *(const i32x4*)(src + idx*8);
    }
    for (int idx = tid; idx < 112; idx += 256){       // rows 82..95
      int r = 82 + (idx >> 3), c = idx & 7;
      *(i32x4*)(xnL + r*128 + ((c*16) ^ ((r&7)<<4))) = (i32x4){0,0,0,0};
    }
  }
  __syncthreads();

  f32x4 acc[6][3];
  #pragma unroll
  for (int i=0;i<6;i++)
    #pragma unroll
    for (int w=0;w<3;w++) acc[i][w] = (f32x4){0.f,0.f,0.f,0.f};

  #pragma unroll
  for (int rt=0;rt<6;rt++){
    int row = rt*16 + lr;
    bf16x8 afr[2];
    #pragma unroll
    for (int kk=0;kk<2;kk++)
      afr[kk] = *(const bf16x8*)(xnL + row*128 + ((kk*64 + lq*16) ^ ((row&7)<<4)));
    #pragma unroll
    for (int kk=0;kk<2;kk++)
      #pragma unroll
      for (int w=0;w<3;w++)
        acc[rt][w] = __builtin_amdgcn_mfma_f32_16x16x32_bf16(afr[kk], bfr[w][kk], acc[rt][w], 0, 0, 0);
  }

  // epilogue: lane holds (B0, C, Draw) for d = wv*16+lr at token t
  {
    int d = wv*16 + lr;
    float bB = bbv[d], bC = bcv[d], bD = bdv[d];
    #pragma unroll
    for (int rt=0;rt<6;rt++){
      #pragma unroll
      for (int e=0;e<4;e++){
        int t = rt*16 + lq*4 + e;
        if (t < 82){
          float B0 = acc[rt][0][e] + bB;
          float Cv = acc[rt][1][e] + bC;
          float Dr = acc[rt][2][e] + bD + delta_p[t*64+d];
          float D  = 1.f/(1.f + __expf(-Dr));
          float xv = bf2f(*(const u16*)(xnL + t*128 + ((d*2) ^ ((t&7)<<4))));
          AxL[t][d] = f2bf(D * A_p[t*64+d]);
          BxL[t][d] = f2bf(D * B0 * xv);
          CxL[t][d] = f2bf(Cv);
        }
      }
    }
  }
  __syncthreads();

  if (wv == 0){
    int d = ln;
    float sq = sqs[(size_t)b*64 + d];
    float s = 0.f, racc = 0.f;
    for (int t = 0; t < 82; t++){
      float a  = bf2f(AxL[t][d]);
      float bx = bf2f(BxL[t][d]);
      float c  = bf2f(CxL[t][d]);
      float xv = bf2f(*(const u16*)(xnL + t*128 + ((d*2) ^ ((t&7)<<4))));
      s = fmaf(a, s, bx);
      float o = fmaf(c, s, sq*xv);
      float z = 1.f/(1.f + __expf(-xv));
      racc = fmaf(o, z, racc);
    }
    float pooled = (tsum[(size_t)b*64 + d] + racc) * (1.f/82.f);
    float s1 = pooled, s2v = pooled*pooled;
    #pragma unroll
    for (int off=32; off>0; off>>=1){ s1 += __shfl_xor(s1, off, 64); s2v += __shfl_xor(s2v, off, 64); }
    float mean = s1*(1.f/64.f), var = s2v*(1.f/64.f) - mean*mean;
    float yn = (pooled - mean)*rsqrtf(var + 1e-5f)*ln2_g[d] + ln2_b[d];
    float a1 = bm1[d];
    for (int k=0;k<64;k++) a1 = fmaf(__shfl(yn, k, 64), Wm1[k*64+d], a1);
    float hg = 0.5f*a1*(1.f + erff(a1*0.70710678118654752f));
    float a2 = bm2[d];
    for (int k=0;k<64;k++) a2 = fmaf(__shfl(hg, k, 64), Wm2[k*64+d], a2);
    out[(size_t)b*64 + d] = pooled + a2;
  }
}

extern "C" void kernel_launch(void* const* d_in, const int* in_sizes, int n_in,
                              void* d_out, int out_size, void* d_ws, size_t ws_size,
                              hipStream_t stream){
  const float* x       = (const float*)d_in[0];
  const float* w3      = (const float*)d_in[1];
  const float* b3      = (const float*)d_in[2];
  const float* g3      = (const float*)d_in[3];
  const float* be3     = (const float*)d_in[4];
  const float* m3      = (const float*)d_in[5];
  const float* v3      = (const float*)d_in[6];
  const float* w2c     = (const float*)d_in[7];
  const float* b2c     = (const float*)d_in[8];
  const float* g2      = (const float*)d_in[9];
  const float* be2     = (const float*)d_in[10];
  const float* m2      = (const float*)d_in[11];
  const float* v2      = (const float*)d_in[12];
  const float* pos_emb = (const float*)d_in[13];
  const float* cls_tok = (const float*)d_in[14];
  const float* ln1_g   = (const float*)d_in[15];
  const float* ln1_b   = (const float*)d_in[16];
  const float* Wb      = (const float*)d_in[17];
  const float* bbv     = (const float*)d_in[18];
  const float* Wc      = (const float*)d_in[19];
  const float* bc      = (const float*)d_in[20];
  const float* Wd      = (const float*)d_in[21];
  const float* bd      = (const float*)d_in[22];
  const float* delta_p = (const float*)d_in[23];
  const float* A_p     = (const float*)d_in[24];
  const float* Wst     = (const float*)d_in[25];
  const float* bst     = (const float*)d_in[26];
  const float* bias_st = (const float*)d_in[27];
  const float* ln2_g   = (const float*)d_in[28];
  const float* ln2_b   = (const float*)d_in[29];
  const float* Wm1     = (const float*)d_in[30];
  const float* bm1     = (const float*)d_in[31];
  const float* Wm2     = (const float*)d_in[32];
  const float* bm2     = (const float*)d_in[33];

  // workspace layout (bytes), peak = 204,660,736:
  //   Wt2  [159252480,  159547392)  (wt -> k_cv23)
  //   xn   [159571968,  202563584)  bf16 [4096][82][64]  (k_cv23 -> k_fuse)
  //   tsum [202563584,  203612160)  f32  [4096][64]      (k_cv23 -> k_fuse)
  //   sqs  [203612160,  204660736)  f32  [4096][64]      (k_cv23 -> k_fuse)
  char* ws = (char*)d_ws;
  u16*   Wt2  = (u16*)(ws + 159252480);
  u16*   xnb  = (u16*)(ws + 159571968);
  float* tsum = (float*)(ws + 202563584);
  float* sqs  = (float*)(ws + 203612160);

  k_wt   <<<576,  256, 0, stream>>>(w2c, g2, v2, Wt2);
  k_cv23 <<<2048, 256, 0, stream>>>(x, w3, b3, g3, be3, m3, v3, Wt2,
                                    b2c, g2, be2, m2, v2,
                                    pos_emb, cls_tok, ln1_g, ln1_b,
                                    Wst, bst, bias_st, xnb, tsum, sqs);
  k_fuse <<<4096, 256, 0, stream>>>(xnb, tsum, sqs, Wb, Wc, Wd, bbv, bc, bd,
                                    delta_p, A_p, ln2_g, ln2_b,
                                    Wm1, bm1, Wm2, bm2, (float*)d_out);
}

// Round 17
// 359.323 us; speedup vs baseline: 2.0420x; 1.9053x over previous
//
#include <hip/hip_runtime.h>

typedef unsigned short u16;
typedef unsigned int u32;
typedef __attribute__((ext_vector_type(8))) short bf16x8;
typedef __attribute__((ext_vector_type(4))) float f32x4;
typedef __attribute__((ext_vector_type(4))) int i32x4;

#define DEV __device__ __forceinline__

DEV u16 f2bf(float f){
  unsigned u = __float_as_uint(f);
  u += 0x7fffu + ((u >> 16) & 1u);
  return (u16)(u >> 16);
}
DEV float bf2f(u16 h){ return __uint_as_float(((unsigned)h) << 16); }

// Inverse spiral map: pixel index (0..80) -> spiral token position (0..80).
DEV int spiral_t(int pix){
  int px = pix / 9, py = pix % 9;
  int dr = px - 4, dc = py - 4;
  int ar = dr < 0 ? -dr : dr, ac = dc < 0 ? -dc : dc;
  int r = ar > ac ? ar : ac;
  if (r == 0) return 0;
  int start = 1 + 4*r*(r-1);
  if (dr == -r && dc >= -r+1) return start + dc + r - 1;
  if (dc == r)  return start + 2*r + dr + r - 1;
  if (dr == r)  return start + 4*r + dc + r;
  return start + 6*r + dr + r;
}

// ---------------- conv3d (1->8, k=3^3, SAME) + BN + ReLU -> h1 bf16 [B][81][240]
// v3 (round-14): thread owns a (pix,co) column; 27 weights in VGPRs; dd-sliding
// 3-slice register window; 30 outputs -> 15 dword stores.
// MERGED: blocks >= 4096 run the k_wt transform (Wt2 prep) instead -- saves a launch.
__global__ __launch_bounds__(256) void k_conv3d(const float* __restrict__ x,
    const float* __restrict__ w3, const float* __restrict__ b3,
    const float* __restrict__ g3, const float* __restrict__ be3,
    const float* __restrict__ m3, const float* __restrict__ v3,
    const float* __restrict__ w2c, const float* __restrict__ g2,
    const float* __restrict__ v2,
    u16* __restrict__ h1, u16* __restrict__ Wt2){
  __shared__ float tile[3993];   // 33 slices x 121 ([dd+1][px+1][py+1], zero-padded)
  __shared__ float wle[216];
  __shared__ float sc[8], sh[8];
  int b = blockIdx.x, tid = threadIdx.x;

  if (b >= 4096){                // ---- wt blocks ----
    int idx = (b - 4096)*256 + tid;
    int kk = idx & 31;
    int o  = (idx >> 5) & 63;
    int tile2 = idx >> 11;        // 0..71
    int dxy = tile2 >> 3;
    int chunk = tile2 & 7;
    int ch = chunk*32 + kk;
    float v = 0.f;
    if (ch < 240){
      float s2 = g2[o] * rsqrtf(v2[o] + 1e-5f);
      v = w2c[(o*240 + ch)*9 + dxy] * s2;
    }
    Wt2[idx] = f2bf(v);
    return;
  }

  for (int i = tid; i < 3993; i += 256) tile[i] = 0.f;
  if (tid < 216) wle[tid] = w3[tid];
  if (tid < 8){
    float s = g3[tid]*rsqrtf(v3[tid]+1e-5f);
    sc[tid] = s;
    sh[tid] = (b3[tid]-m3[tid])*s + be3[tid];
  }
  __syncthreads();
  const float* xin = x + b*2430;
  for (int i = tid; i < 2430; i += 256){
    int dd = i / 81, rem = i % 81;
    int px = rem / 9, py = rem % 9;
    tile[(dd+1)*121 + (px+1)*11 + (py+1)] = xin[i];
  }
  __syncthreads();
  u16* hb = h1 + (size_t)b*19440;

  for (int col = tid; col < 648; col += 256){
    int pix = col >> 3, co = col & 7;
    int px = pix / 9, py = pix % 9;
    const float* base = tile + px*11 + py;     // slice s at base + s*121
    float wp[27];
    #pragma unroll
    for (int q=0;q<27;q++) wp[q] = wle[co*27+q];
    float scv = sc[co], shv = sh[co];

    float s0[9], s1[9], s2[9];
#define LSL(S, SL)                                                            \
    { const float* tp2 = base + (SL)*121;                                     \
      _Pragma("unroll")                                                       \
      for (int kx=0;kx<3;kx++)                                                \
        _Pragma("unroll")                                                     \
        for (int ky=0;ky<3;ky++) S[kx*3+ky] = tp2[kx*11+ky]; }
#define DOT3(A, SA, SB, SC)                                                   \
    { A = 0.f;                                                                \
      _Pragma("unroll")                                                       \
      for (int q=0;q<9;q++) A = fmaf(SA[q], wp[q], A);                        \
      _Pragma("unroll")                                                       \
      for (int q=0;q<9;q++) A = fmaf(SB[q], wp[9+q], A);                      \
      _Pragma("unroll")                                                       \
      for (int q=0;q<9;q++) A = fmaf(SC[q], wp[18+q], A); }

    LSL(s0, 0); LSL(s1, 1); LSL(s2, 2);
    u16 outv[30];
    #pragma unroll
    for (int d3 = 0; d3 < 30; d3 += 3){
      float a;
      DOT3(a, s0, s1, s2);
      outv[d3] = f2bf(fmaxf(fmaf(a, scv, shv), 0.f));
      LSL(s0, d3+3);
      DOT3(a, s1, s2, s0);
      outv[d3+1] = f2bf(fmaxf(fmaf(a, scv, shv), 0.f));
      LSL(s1, d3+4);
      DOT3(a, s2, s0, s1);
      outv[d3+2] = f2bf(fmaxf(fmaf(a, scv, shv), 0.f));
      LSL(s2, d3+5);                 // max slice index 32 -> in-bounds (33 slices)
    }
#undef LSL
#undef DOT3
    u32* dst = (u32*)(hb + pix*240 + co*30);
    #pragma unroll
    for (int q=0;q<15;q++) dst[q] = ((u32)outv[2*q+1] << 16) | (u32)outv[2*q];
  }
}

// ---------------- conv2d MFMA GEMM + BN + ReLU + pos_emb + FUSED LN1/tsum/SToken
// v9 (round-11/14): depth-2 B pipeline (3-buffer rotation), setprio around
// MFMA clusters, split-k squeeze.
__global__ __launch_bounds__(256, 2) void k_conv2d(const u16* __restrict__ h1,
    const u16* __restrict__ Wt2,
    const float* __restrict__ b2c, const float* __restrict__ g2,
    const float* __restrict__ be2, const float* __restrict__ m2,
    const float* __restrict__ v2,
    const float* __restrict__ pos_emb, const float* __restrict__ cls_tok,
    const float* __restrict__ ln1_g, const float* __restrict__ ln1_b,
    const float* __restrict__ Wst, const float* __restrict__ bst,
    const float* __restrict__ bias_st,
    u16* __restrict__ xn, float* __restrict__ tsum, float* __restrict__ sqs){
  // rows r in [0,162) at r*496 (480B data + 16B zero-ch-pad); zrow (496B zeros) at 80352
  __shared__ __align__(16) char smem[80848];
  const int ZROW = 80352;
  int tid = threadIdx.x;
  int wv = tid >> 6, ln = tid & 63;
  int lq = ln >> 4, lr = ln & 15;
  int img0 = blockIdx.x*2;
  size_t grow0 = (size_t)img0*81;

  int bln = lr*32 + lq*8;    // u16 offset of this lane's B-frag within a [64o][32k] tile

#define LOADB(TAP, C, B)                                                        \
    { const u16* Bt_ = Wt2 + (TAP)*16384 + bln;                                 \
      _Pragma("unroll")                                                         \
      for (int kk=0;kk<2;kk++)                                                  \
        _Pragma("unroll")                                                       \
        for (int j=0;j<4;j++)                                                   \
          B[kk][j] = *(const bf16x8*)(Bt_ + ((C)*2+kk)*2048 + j*512); }

  // B prologue (tap0 chunks 0,1,2) issued BEFORE the barrier
  bf16x8 bB0[2][4], bB1[2][4], bB2[2][4];
  LOADB(0, 0, bB0);
  LOADB(0, 1, bB1);
  LOADB(0, 2, bB2);

  for (int r = tid; r < 162; r += 256)
    *(i32x4*)(smem + r*496 + 480) = (i32x4){0,0,0,0};
  if (tid < 31) *(i32x4*)(smem + ZROW + tid*16) = (i32x4){0,0,0,0};
  {
    const u16* src = h1 + grow0*240;
    for (int idx = tid; idx < 162*30; idx += 256){
      int r = idx / 30, c = idx % 30;
      *(i32x4*)(smem + r*496 + c*16) = *(const i32x4*)(src + idx*8);
    }
  }
  __syncthreads();

  f32x4 acc[3][4];
  #pragma unroll
  for (int i=0;i<3;i++)
    #pragma unroll
    for (int j=0;j<4;j++) acc[i][j] = (f32x4){0.f,0.f,0.f,0.f};

#define CALCADDR(TAP, A0, A1, A13)                                              \
  { int dx = (TAP)/3 - 1, dy = (TAP)%3 - 1;                                     \
    _Pragma("unroll")                                                           \
    for (int rt=0;rt<3;rt++){                                                   \
      int row = (wv*3+rt)*16 + lr;                                              \
      int pix = row % 81;                                                       \
      int px = pix/9, py = pix%9;                                               \
      int px2 = px + dx, py2 = py + dy;                                         \
      bool valid = (row < 162) && ((unsigned)px2 < 9u) && ((unsigned)py2 < 9u); \
      int nrow = (row - pix) + px2*9 + py2;                                     \
      int base = valid ? nrow*496 : ZROW;                                       \
      A0[rt]  = base + lq*16;                                                   \
      A1[rt]  = base + 64 + lq*16;                                              \
      A13[rt] = (lq == 3) ? ZROW : (A1[rt] + 384);                              \
    } }

#define LOADA(C, SA0, SA1, SA13, A0, A1)                                        \
    { _Pragma("unroll")                                                         \
      for (int rt=0;rt<3;rt++){                                                 \
        A0[rt] = *(const bf16x8*)(smem + SA0[rt] + (C)*128);                    \
        A1[rt] = *(const bf16x8*)(smem + ((C)==3 ? SA13[rt]                     \
                                                 : SA1[rt] + (C)*128)); } }

#define DOMFMA(B, A0, A1)                                                       \
    { __builtin_amdgcn_s_setprio(1);                                            \
      _Pragma("unroll")                                                         \
      for (int rt=0;rt<3;rt++)                                                  \
        _Pragma("unroll")                                                       \
        for (int j=0;j<4;j++)                                                   \
          acc[rt][j] = __builtin_amdgcn_mfma_f32_16x16x32_bf16(A0[rt], B[0][j], acc[rt][j], 0, 0, 0); \
      _Pragma("unroll")                                                         \
      for (int rt=0;rt<3;rt++)                                                  \
        _Pragma("unroll")                                                       \
        for (int j=0;j<4;j++)                                                   \
          acc[rt][j] = __builtin_amdgcn_mfma_f32_16x16x32_bf16(A1[rt], B[1][j], acc[rt][j], 0, 0, 0); \
      __builtin_amdgcn_s_setprio(0); }

#define TAPBODY(TAPV, BA, BB, BC)                                               \
  { int ntap_ = (TAPV) < 8 ? (TAPV)+1 : 8;                                      \
    DOMFMA(BA, aAX0, aAX1);                                                     \
    LOADB((TAPV), 3, BA); LOADA(2, aC0, aC1, aC13, aAX0, aAX1);                 \
    DOMFMA(BB, aAY0, aAY1);                                                     \
    LOADB(ntap_, 0, BB); CALCADDR(ntap_, aN0, aN1, aN13);                       \
    LOADA(3, aC0, aC1, aC13, aAY0, aAY1);                                       \
    DOMFMA(BC, aAX0, aAX1);                                                     \
    LOADB(ntap_, 1, BC); LOADA(0, aN0, aN1, aN13, aAX0, aAX1);                  \
    DOMFMA(BA, aAY0, aAY1);                                                     \
    LOADB(ntap_, 2, BA); LOADA(1, aN0, aN1, aN13, aAY0, aAY1);                  \
    _Pragma("unroll")                                                           \
    for (int rt=0;rt<3;rt++){ aC0[rt]=aN0[rt]; aC1[rt]=aN1[rt]; aC13[rt]=aN13[rt]; } }

  int aC0[3], aC1[3], aC13[3];
  int aN0[3], aN1[3], aN13[3];
  bf16x8 aAX0[3], aAX1[3], aAY0[3], aAY1[3];

  CALCADDR(0, aC0, aC1, aC13);
  LOADA(0, aC0, aC1, aC13, aAX0, aAX1);
  LOADA(1, aC0, aC1, aC13, aAY0, aAY1);

  for (int t3 = 0; t3 < 9; t3 += 3){
    TAPBODY(t3+0, bB0, bB1, bB2);
    TAPBODY(t3+1, bB1, bB2, bB0);
    TAPBODY(t3+2, bB2, bB0, bB1);
  }
#undef CALCADDR
#undef LOADB
#undef LOADA
#undef DOMFMA
#undef TAPBODY

  __syncthreads();   // all image-LDS reads done; smem reusable for reductions

  float t2c[4], lg[4], lb[4];
  #pragma unroll
  for (int j=0;j<4;j++){
    int col = j*16 + lr;
    float s2 = g2[col]*rsqrtf(v2[col]+1e-5f);
    t2c[j] = (b2c[col]-m2[col])*s2 + be2[col];
    lg[j] = ln1_g[col]; lb[j] = ln1_b[col];
  }

  float st0[4]={0,0,0,0}, st1[4]={0,0,0,0};
  float sx0[4]={0,0,0,0}, sx1[4]={0,0,0,0};

  #pragma unroll
  for (int rt=0;rt<3;rt++){
    #pragma unroll
    for (int e=0;e<4;e++){
      int row = (wv*3+rt)*16 + lq*4 + e;
      if (row < 162){
        int im = (row >= 81);
        int pix = row - im*81;
        int tsp = spiral_t(pix);
        const float* pe = pos_emb + (1+tsp)*64;
        float y[4], m1 = 0.f, m2v = 0.f;
        #pragma unroll
        for (int j=0;j<4;j++){
          y[j] = fmaxf(acc[rt][j][e] + t2c[j], 0.f) + pe[j*16+lr];
          m1 += y[j]; m2v = fmaf(y[j], y[j], m2v);
        }
        #pragma unroll
        for (int off=1; off<16; off<<=1){
          m1  += __shfl_xor(m1,  off, 64);
          m2v += __shfl_xor(m2v, off, 64);
        }
        float mean = m1*(1.f/64.f);
        float var  = m2v*(1.f/64.f) - mean*mean;
        float rs = rsqrtf(var + 1e-5f);
        u16* dst = xn + ((size_t)(img0+im)*82 + 1 + tsp)*64;
        #pragma unroll
        for (int j=0;j<4;j++){
          float xnv = (y[j]-mean)*rs*lg[j] + lb[j];
          dst[j*16+lr] = f2bf(xnv);
          if (im == 0){ st0[j] += y[j]; sx0[j] += xnv; }
          else        { st1[j] += y[j]; sx1[j] += xnv; }
        }
      }
    }
  }

  #pragma unroll
  for (int j=0;j<4;j++){
    st0[j] += __shfl_xor(st0[j],16,64); st0[j] += __shfl_xor(st0[j],32,64);
    st1[j] += __shfl_xor(st1[j],16,64); st1[j] += __shfl_xor(st1[j],32,64);
    sx0[j] += __shfl_xor(sx0[j],16,64); sx0[j] += __shfl_xor(sx0[j],32,64);
    sx1[j] += __shfl_xor(sx1[j],16,64); sx1[j] += __shfl_xor(sx1[j],32,64);
  }
  float* partT = (float*)smem;            // [4 wv][2 img][64 d]
  float* partX = (float*)(smem + 2048);
  float* xsumL = (float*)(smem + 4096);
  if (lq == 0){
    #pragma unroll
    for (int j=0;j<4;j++){
      partT[wv*128 +       j*16+lr] = st0[j];
      partT[wv*128 + 64  + j*16+lr] = st1[j];
      partX[wv*128 +       j*16+lr] = sx0[j];
      partX[wv*128 + 64  + j*16+lr] = sx1[j];
    }
  }
  __syncthreads();
  if (tid < 128){
    int im = tid >> 6, d = tid & 63;
    float tt = partT[im*64+d] + partT[128+im*64+d] + partT[256+im*64+d] + partT[384+im*64+d];
    float xx = partX[im*64+d] + partX[128+im*64+d] + partX[256+im*64+d] + partX[384+im*64+d];
    float clsv = cls_tok[d] + pos_emb[d];
    float c1v = clsv, c2v = clsv*clsv;
    #pragma unroll
    for (int off=1; off<64; off<<=1){ c1v += __shfl_xor(c1v, off, 64); c2v += __shfl_xor(c2v, off, 64); }
    float cm = c1v*(1.f/64.f), cv = c2v*(1.f/64.f) - cm*cm;
    float cxn = (clsv - cm)*rsqrtf(cv + 1e-5f)*ln1_g[d] + ln1_b[d];
    xn[((size_t)(img0+im)*82)*64 + d] = f2bf(cxn);
    tsum[(size_t)(img0+im)*64 + d] = tt + clsv;
    xsumL[im*64 + d] = (xx + cxn) * (1.f/82.f);
  }
  __syncthreads();
  {
    int im = tid >> 7, d2 = tid & 127;
    int d = d2 >> 1, half = d2 & 1;
    float a = 0.f;
    int k0 = half*32;
    #pragma unroll
    for (int k=0;k<32;k++) a = fmaf(xsumL[im*64 + k0+k], Wst[(k0+k)*64+d], a);
    a += __shfl_xor(a, 1, 64);
    if (half == 0){
      a += bst[d];
      a = fmaxf(a, 0.f);
      a = 1.f/(1.f + __expf(-a));
      sqs[(size_t)(img0+im)*64 + d] = a + bias_st[d];
    }
  }
}

// ---------------- FUSED B/C/delta GEMM + S6 prep + scan + pool + LN2 + MLP (block = batch)
__global__ __launch_bounds__(256, 2) void k_fuse(const u16* __restrict__ xn,
    const float* __restrict__ tsum, const float* __restrict__ sqs,
    const float* __restrict__ Wb, const float* __restrict__ Wc, const float* __restrict__ Wd,
    const float* __restrict__ bbv, const float* __restrict__ bcv, const float* __restrict__ bdv,
    const float* __restrict__ delta_p, const float* __restrict__ A_p,
    const float* __restrict__ ln2_g, const float* __restrict__ ln2_b,
    const float* __restrict__ Wm1, const float* __restrict__ bm1,
    const float* __restrict__ Wm2, const float* __restrict__ bm2,
    float* __restrict__ out){
  __shared__ __align__(16) char xnL[96*128];   // swizzled rows: byte ^ ((row&7)<<4)
  __shared__ u16 AxL[96][66], BxL[96][66], CxL[96][66];
  int tid = threadIdx.x;
  int wv = tid >> 6, ln = tid & 63;
  int lq = ln >> 4, lr = ln & 15;
  int b = blockIdx.x;

  // B-frags first (L2-hot): cc = wv*16+lr for each of Wb/Wc/Wd
  bf16x8 bfr[3][2];
  {
    int cc = wv*16 + lr;
    const float* Ws[3] = {Wb, Wc, Wd};
    #pragma unroll
    for (int w=0;w<3;w++)
      #pragma unroll
      for (int kk=0;kk<2;kk++){
        int k0 = kk*32 + lq*8;
        bf16x8 f;
        #pragma unroll
        for (int e=0;e<8;e++) f[e] = (short)f2bf(Ws[w][(k0+e)*64 + cc]);
        bfr[w][kk] = f;
      }
  }

  // stage xn[b] rows 0..81 (swizzled), zero rows 82..95
  {
    const u16* src = xn + (size_t)b*82*64;
    for (int idx = tid; idx < 656; idx += 256){       // 82 rows x 8 x 16B
      int r = idx >> 3, c = idx & 7;
      *(i32x4*)(xnL + r*128 + ((c*16) ^ ((r&7)<<4))) = *(const i32x4*)(src + idx*8);
    }
    for (int idx = tid; idx < 112; idx += 256){       // rows 82..95
      int r = 82 + (idx >> 3), c = idx & 7;
      *(i32x4*)(xnL + r*128 + ((c*16) ^ ((r&7)<<4))) = (i32x4){0,0,0,0};
    }
  }
  __syncthreads();

  f32x4 acc[6][3];
  #pragma unroll
  for (int i=0;i<6;i++)
    #pragma unroll
    for (int w=0;w<3;w++) acc[i][w] = (f32x4){0.f,0.f,0.f,0.f};

  #pragma unroll
  for (int rt=0;rt<6;rt++){
    int row = rt*16 + lr;
    bf16x8 afr[2];
    #pragma unroll
    for (int kk=0;kk<2;kk++)
      afr[kk] = *(const bf16x8*)(xnL + row*128 + ((kk*64 + lq*16) ^ ((row&7)<<4)));
    #pragma unroll
    for (int kk=0;kk<2;kk++)
      #pragma unroll
      for (int w=0;w<3;w++)
        acc[rt][w] = __builtin_amdgcn_mfma_f32_16x16x32_bf16(afr[kk], bfr[w][kk], acc[rt][w], 0, 0, 0);
  }

  // epilogue: lane holds (B0, C, Draw) for d = wv*16+lr at token t
  {
    int d = wv*16 + lr;
    float bB = bbv[d], bC = bcv[d], bD = bdv[d];
    #pragma unroll
    for (int rt=0;rt<6;rt++){
      #pragma unroll
      for (int e=0;e<4;e++){
        int t = rt*16 + lq*4 + e;
        if (t < 82){
          float B0 = acc[rt][0][e] + bB;
          float Cv = acc[rt][1][e] + bC;
          float Dr = acc[rt][2][e] + bD + delta_p[t*64+d];
          float D  = 1.f/(1.f + __expf(-Dr));
          float xv = bf2f(*(const u16*)(xnL + t*128 + ((d*2) ^ ((t&7)<<4))));
          AxL[t][d] = f2bf(D * A_p[t*64+d]);
          BxL[t][d] = f2bf(D * B0 * xv);
          CxL[t][d] = f2bf(Cv);
        }
      }
    }
  }
  __syncthreads();

  if (wv == 0){
    int d = ln;
    float sq = sqs[(size_t)b*64 + d];
    float s = 0.f, racc = 0.f;
    for (int t = 0; t < 82; t++){
      float a  = bf2f(AxL[t][d]);
      float bx = bf2f(BxL[t][d]);
      float c  = bf2f(CxL[t][d]);
      float xv = bf2f(*(const u16*)(xnL + t*128 + ((d*2) ^ ((t&7)<<4))));
      s = fmaf(a, s, bx);
      float o = fmaf(c, s, sq*xv);
      float z = 1.f/(1.f + __expf(-xv));
      racc = fmaf(o, z, racc);
    }
    float pooled = (tsum[(size_t)b*64 + d] + racc) * (1.f/82.f);
    float s1 = pooled, s2v = pooled*pooled;
    #pragma unroll
    for (int off=32; off>0; off>>=1){ s1 += __shfl_xor(s1, off, 64); s2v += __shfl_xor(s2v, off, 64); }
    float mean = s1*(1.f/64.f), var = s2v*(1.f/64.f) - mean*mean;
    float yn = (pooled - mean)*rsqrtf(var + 1e-5f)*ln2_g[d] + ln2_b[d];
    float a1 = bm1[d];
    for (int k=0;k<64;k++) a1 = fmaf(__shfl(yn, k, 64), Wm1[k*64+d], a1);
    float hg = 0.5f*a1*(1.f + erff(a1*0.70710678118654752f));
    float a2 = bm2[d];
    for (int k=0;k<64;k++) a2 = fmaf(__shfl(hg, k, 64), Wm2[k*64+d], a2);
    out[(size_t)b*64 + d] = pooled + a2;
  }
}

extern "C" void kernel_launch(void* const* d_in, const int* in_sizes, int n_in,
                              void* d_out, int out_size, void* d_ws, size_t ws_size,
                              hipStream_t stream){
  const float* x       = (const float*)d_in[0];
  const float* w3      = (const float*)d_in[1];
  const float* b3      = (const float*)d_in[2];
  const float* g3      = (const float*)d_in[3];
  const float* be3     = (const float*)d_in[4];
  const float* m3      = (const float*)d_in[5];
  const float* v3      = (const float*)d_in[6];
  const float* w2c     = (const float*)d_in[7];
  const float* b2c     = (const float*)d_in[8];
  const float* g2      = (const float*)d_in[9];
  const float* be2     = (const float*)d_in[10];
  const float* m2      = (const float*)d_in[11];
  const float* v2      = (const float*)d_in[12];
  const float* pos_emb = (const float*)d_in[13];
  const float* cls_tok = (const float*)d_in[14];
  const float* ln1_g   = (const float*)d_in[15];
  const float* ln1_b   = (const float*)d_in[16];
  const float* Wb      = (const float*)d_in[17];
  const float* bbv     = (const float*)d_in[18];
  const float* Wc      = (const float*)d_in[19];
  const float* bc      = (const float*)d_in[20];
  const float* Wd      = (const float*)d_in[21];
  const float* bd      = (const float*)d_in[22];
  const float* delta_p = (const float*)d_in[23];
  const float* A_p     = (const float*)d_in[24];
  const float* Wst     = (const float*)d_in[25];
  const float* bst     = (const float*)d_in[26];
  const float* bias_st = (const float*)d_in[27];
  const float* ln2_g   = (const float*)d_in[28];
  const float* ln2_b   = (const float*)d_in[29];
  const float* Wm1     = (const float*)d_in[30];
  const float* bm1     = (const float*)d_in[31];
  const float* Wm2     = (const float*)d_in[32];
  const float* bm2     = (const float*)d_in[33];

  // workspace layout (bytes), peak = 204,660,736:
  //   h1   [0,          159252480)  (conv3d -> conv2d)
  //   Wt2  [159252480,  159547392)  (conv3d wt-blocks -> conv2d)
  //   xn   [159571968,  202563584)  bf16 [4096][82][64]  (conv2d -> k_fuse)
  //   tsum [202563584,  203612160)  f32  [4096][64]      (conv2d -> k_fuse)
  //   sqs  [203612160,  204660736)  f32  [4096][64]      (conv2d -> k_fuse)
  char* ws = (char*)d_ws;
  u16*   h1   = (u16*)ws;
  u16*   Wt2  = (u16*)(ws + 159252480);
  u16*   xnb  = (u16*)(ws + 159571968);
  float* tsum = (float*)(ws + 202563584);
  float* sqs  = (float*)(ws + 203612160);

  k_conv3d<<<4672, 256, 0, stream>>>(x, w3, b3, g3, be3, m3, v3,
                                     w2c, g2, v2, h1, Wt2);
  k_conv2d<<<2048, 256, 0, stream>>>(h1, Wt2, b2c, g2, be2, m2, v2,
                                     pos_emb, cls_tok, ln1_g, ln1_b,
                                     Wst, bst, bias_st, xnb, tsum, sqs);
  k_fuse  <<<4096, 256, 0, stream>>>(xnb, tsum, sqs, Wb, Wc, Wd, bbv, bc, bd,
                                     delta_p, A_p, ln2_g, ln2_b,
                                     Wm1, bm1, Wm2, bm2, (float*)d_out);
}